// Round 9
// baseline (1040.735 us; speedup 1.0000x reference)
//
#include <hip/hip_runtime.h>
#include <stdint.h>

// CGIterator on MI355X (gfx950) — block-fused v7: round-6 structure, but
// mixed2 is staged in a third LDS buffer (B2s) instead of 20 packed VGPRs.
// Persistent reg state = cur[10] only -> fits the 128-VGPR cap, no spill
// (rounds 5-8 spilled ~490MB/launch; attributes couldn't raise the cap).
// LDS: As 32KB | Bs 32KB | B2s 32KB = 96KB (1 block/CU, same as measured).
// Stream storage: offset = l*l*NK + (n*(2l+1)+loc)*128 + k, NK = N*K.

#define NK (16384 * 128)

typedef float f32x4 __attribute__((ext_vector_type(4)));
typedef short short8 __attribute__((ext_vector_type(8)));
typedef __bf16 bf16x8 __attribute__((ext_vector_type(8)));

typedef short8 short8a __attribute__((may_alias));
typedef f32x4 f32x4a __attribute__((may_alias));
typedef uint32_t u32a __attribute__((may_alias));
typedef uint16_t u16a __attribute__((may_alias));
typedef float floata __attribute__((may_alias));

__device__ __forceinline__ uint16_t f2b(float f) {   // f32 -> bf16 bits, RNE
  uint32_t u = __builtin_bit_cast(uint32_t, f);
  u += 0x7FFFu + ((u >> 16) & 1u);
  return (uint16_t)(u >> 16);
}
__device__ __forceinline__ float b2f(uint16_t h) {
  uint32_t u = ((uint32_t)h) << 16;
  return __builtin_bit_cast(float, u);
}
__device__ __forceinline__ f32x4 mfma_bf16(short8 a, short8 b, f32x4 c) {
  return __builtin_amdgcn_mfma_f32_16x16x32_bf16(
      __builtin_bit_cast(bf16x8, a), __builtin_bit_cast(bf16x8, b), c, 0, 0, 0);
}
__device__ __forceinline__ int l_of_m(int m) { return (m > 0) + (m > 3) + (m > 8); }
__device__ __forceinline__ int l_of_t(int t) { return (t >= 1) + (t >= 3) + (t >= 6); }

// Tile-row decode. 16-row tiles per l: t0:l0, t1-2:l1, t3-5:l2, t6-9:l3.
// Returns As row index n*16 + m_flat; pad slots clamp to row 0 (real=false).
__device__ __forceinline__ int trow(int t, int ridx, bool& real) {
  const int l = l_of_t(t);
  const int deg = 2 * l + 1;
  const int p0 = (t - (l * (l + 1)) / 2) * 16 + ridx;
  real = p0 < 8 * deg;
  const int p = real ? p0 : 0;
  const int n = p / deg;
  const int mloc = p - n * deg;
  return n * 16 + l * l + mloc;
}

// As byte address with XOR swizzle. row>>3 term matters: l0 rows are n*16,
// so (row&7) alone is constant-0 there.
__device__ __forceinline__ int aswz(int row, int kbyte) {
  return row * 256 + (kbyte ^ (((row ^ (row >> 3)) & 7) << 4));
}

// GEMM, accumulate: acc[t] += A(tile t) @ W_{l(t)}, output col qt*16+r.
__device__ __forceinline__ void gemm_app(const char* AsB, const uint16_t* Wb,
                                         int r, int g, int qt, f32x4* acc) {
#pragma unroll
  for (int lg = 0; lg < 4; ++lg) {
    const uint16_t* Wq = Wb + lg * 16384 + (qt * 16 + r) * 128 + g * 8;
    const short8 w0 = *(const short8a*)(Wq);
    const short8 w1 = *(const short8a*)(Wq + 32);
    const short8 w2 = *(const short8a*)(Wq + 64);
    const short8 w3 = *(const short8a*)(Wq + 96);
#pragma unroll
    for (int u = 0; u <= lg; ++u) {
      const int t = lg * (lg + 1) / 2 + u;
      bool dum;
      const int arow = trow(t, r, dum);
      f32x4 c = acc[t];
      c = mfma_bf16(*(const short8a*)(AsB + aswz(arow, g * 16)), w0, c);
      c = mfma_bf16(*(const short8a*)(AsB + aswz(arow, 64 + g * 16)), w1, c);
      c = mfma_bf16(*(const short8a*)(AsB + aswz(arow, 128 + g * 16)), w2, c);
      c = mfma_bf16(*(const short8a*)(AsB + aswz(arow, 192 + g * 16)), w3, c);
      acc[t] = c;
    }
  }
}

// GEMM, fresh accumulate, write C-frags (bf16) directly to Bs[n][k][m].
__device__ __forceinline__ void gemm_stage_bs(const char* AsB, const uint16_t* Wb,
                                              int r, int g, int qt,
                                              uint16_t* Bs) {
#pragma unroll
  for (int lg = 0; lg < 4; ++lg) {
    const uint16_t* Wq = Wb + lg * 16384 + (qt * 16 + r) * 128 + g * 8;
    const short8 w0 = *(const short8a*)(Wq);
    const short8 w1 = *(const short8a*)(Wq + 32);
    const short8 w2 = *(const short8a*)(Wq + 64);
    const short8 w3 = *(const short8a*)(Wq + 96);
#pragma unroll
    for (int u = 0; u <= lg; ++u) {
      const int t = lg * (lg + 1) / 2 + u;
      bool dum;
      const int arow = trow(t, r, dum);
      f32x4 c = {0.f, 0.f, 0.f, 0.f};
      c = mfma_bf16(*(const short8a*)(AsB + aswz(arow, g * 16)), w0, c);
      c = mfma_bf16(*(const short8a*)(AsB + aswz(arow, 64 + g * 16)), w1, c);
      c = mfma_bf16(*(const short8a*)(AsB + aswz(arow, 128 + g * 16)), w2, c);
      c = mfma_bf16(*(const short8a*)(AsB + aswz(arow, 192 + g * 16)), w3, c);
#pragma unroll
      for (int j = 0; j < 4; ++j) {
        bool cr;
        const int row = trow(t, g * 4 + j, cr);
        if (cr) {
          const int cn = row >> 4, cm = row & 15;
          Bs[cn * 2048 + (qt * 16 + r) * 16 + cm] = f2b(c[j]);
        }
      }
    }
  }
}

// ---------------------------------------------------------------------------
// K0: prep — bf16-transpose weights ([k][q] -> [q][k]) and build Ccat[16][256].
// ---------------------------------------------------------------------------
__global__ __launch_bounds__(256) void k0_prep(
    const float* __restrict__ mixw, const float* __restrict__ iterw,
    const float* __restrict__ cg,
    uint16_t* __restrict__ wtmix, uint16_t* __restrict__ wtiter,
    uint16_t* __restrict__ ccat) {
  int idx = blockIdx.x * 256 + threadIdx.x;
  const int NMIX = 3 * 4 * 16384, NITR = 2 * 4 * 16384;
  if (idx < NMIX) {
    int il = idx >> 14, rem = idx & 16383, q = rem >> 7, k = rem & 127;
    wtmix[idx] = f2b(mixw[il * 16384 + k * 128 + q]);
  } else if (idx < NMIX + NITR) {
    int o = idx - NMIX;
    int tl = o >> 14, rem = o & 16383, q = rem >> 7, k = rem & 127;
    wtiter[o] = f2b(iterw[tl * 16384 + k * 128 + q]);
  } else if (idx < NMIX + NITR + 4096) {
    int o = idx - NMIX - NITR;
    int mg = o >> 8, ij = o & 255, ig = ij >> 4, jg = ij & 15;
    int l = l_of_m(mg), m = mg - l * l;
    int l1 = l_of_m(ig), i = ig - l1 * l1;
    int l2 = l_of_m(jg), j = jg - l2 * l2;
    ccat[o] = f2b(cg[(l1 * 16 + l2 * 4 + l) * 343 + i * 49 + j * 7 + m]);
  }
}

// ---------------------------------------------------------------------------
// Fused block kernel: 512 threads = 8 waves; wave w owns channel tile qt=w
// for GEMMs and row n=w for the TP.
// LDS 96KB: As [128 row][128 k] bf16 swizzled | Bs [8 n][128 k][16 m] (mixed1)
// | B2s same (mixed2). Final f32 staging overlays As+Bs (first 64KB).
// ---------------------------------------------------------------------------
__global__ __launch_bounds__(512) void k_fused(
    const float* __restrict__ f0, const float* __restrict__ f1,
    const float* __restrict__ f2, const float* __restrict__ f3,
    const uint16_t* __restrict__ wtmix, const uint16_t* __restrict__ wtiter,
    const uint16_t* __restrict__ ccat, float* __restrict__ out) {
  __shared__ __align__(16) uint16_t smem[49152];   // 96KB
  char* const AsB = (char*)smem;        // swizzled [128 row][128 k] bf16
  uint16_t* const Bs = smem + 16384;    // mixed1: Bs[n*2048 + k*16 + m]
  uint16_t* const B2s = smem + 32768;   // mixed2: same layout

  const int tid = threadIdx.x;
  const int lane = tid & 63, wid = tid >> 6;
  const int g = lane >> 4, r = lane & 15;
  const int qt = wid;
  const int nblk = blockIdx.x * 8;

  // zero all LDS (coverage insurance)
  {
    u32a* z = (u32a*)smem;
    for (int i = 0; i < 48; ++i) z[tid + i * 512] = 0;
  }
  __syncthreads();

  // ---- phase 0: stage feats (bf16) into As ----
  for (int i = 0; i < 32; ++i) {
    const int elem = tid + i * 512;
    const int row = elem >> 7, k = elem & 127;
    const int nn = row >> 4, mf = row & 15;
    const int l = l_of_m(mf), loc = mf - l * l;
    const float* F = (l == 0) ? f0 : (l == 1) ? f1 : (l == 2) ? f2 : f3;
    *(u16a*)(AsB + aswz(row, k * 2)) =
        f2b(F[((size_t)(nblk + nn) * (2 * l + 1) + loc) * 128 + k]);
  }
  __syncthreads();

  // ---- mixing: cur = feats@W0 (f32 regs), mixed1 -> Bs, mixed2 -> B2s ----
  f32x4 cur[10];
#pragma unroll
  for (int t = 0; t < 10; ++t) cur[t] = f32x4{0.f, 0.f, 0.f, 0.f};
  gemm_app(AsB, wtmix, r, g, qt, cur);
  gemm_stage_bs(AsB, wtmix + 4 * 16384, r, g, qt, Bs);
  gemm_stage_bs(AsB, wtmix + 8 * 16384, r, g, qt, B2s);
  __syncthreads();   // feats reads done; As may be overwritten

  const int ih = g >> 1, jb = (g & 1) * 8;

#pragma unroll 1
  for (int it = 0; it < 2; ++it) {
    const uint16_t* Bx = (it == 0) ? Bs : B2s;
    // ---- stage cur -> As (bf16) ----
#pragma unroll
    for (int t = 0; t < 10; ++t)
#pragma unroll
      for (int j = 0; j < 4; ++j) {
        bool cr;
        const int row = trow(t, g * 4 + j, cr);
        if (cr) *(u16a*)(AsB + aswz(row, (qt * 16 + r) * 2)) = f2b(cur[t][j]);
      }
    __syncthreads();

    // ---- TP for n = wid: tacc = Ccat(16x256) @ P(256x128), P in-register ----
    f32x4 tacc[8];
#pragma unroll
    for (int ki = 0; ki < 8; ++ki) tacc[ki] = f32x4{0.f, 0.f, 0.f, 0.f};
#pragma unroll
    for (int cc = 0; cc < 8; ++cc) {
      const short8 cfr = *(const short8a*)(ccat + r * 256 + cc * 32 + g * 8);
      const int arow = wid * 16 + cc * 2 + ih;
#pragma unroll
      for (int ki = 0; ki < 8; ++ki) {
        const int k = ki * 16 + r;
        const float av = b2f(*(const u16a*)(AsB + aswz(arow, k * 2)));
        const short8 bv = *(const short8a*)&Bx[wid * 2048 + k * 16 + jb];
        short8 pv;
#pragma unroll
        for (int e = 0; e < 8; ++e)
          pv[e] = (short)f2b(av * b2f((uint16_t)bv[e]));
        tacc[ki] = mfma_bf16(cfr, pv, tacc[ki]);
      }
    }
    __syncthreads();   // all As reads complete before tp overwrite

    // ---- tp -> As rows of n = wid ----
#pragma unroll
    for (int ki = 0; ki < 8; ++ki)
#pragma unroll
      for (int j = 0; j < 4; ++j)
        *(u16a*)(AsB + aswz(wid * 16 + g * 4 + j, (ki * 16 + r) * 2)) =
            f2b(tacc[ki][j]);
    __syncthreads();

    // ---- cur += tp @ iter_w[it] ----
    gemm_app(AsB, wtiter + it * 4 * 16384, r, g, qt, cur);
    __syncthreads();
  }

  // ---- final: stage f32 in LDS (overlay of As+Bs), coalesced store ----
  floata* fs = (floata*)smem;   // [128 row][128 k] f32 = 64KB
#pragma unroll
  for (int t = 0; t < 10; ++t)
#pragma unroll
    for (int j = 0; j < 4; ++j) {
      bool cr;
      const int row = trow(t, g * 4 + j, cr);
      if (cr) fs[row * 128 + qt * 16 + r] = cur[t][j];
    }
  __syncthreads();
  {
    const int grp = tid >> 5, t32 = tid & 31;
    const int ns = grp >> 1, mh = (grp & 1) * 8;
    for (int m8 = 0; m8 < 8; ++m8) {
      const int m = mh + m8;
      const int l = l_of_m(m), loc = m - l * l;
      float* op = out + (size_t)l * l * NK +
                  ((size_t)(nblk + ns) * (2 * l + 1) + loc) * 128 + t32 * 4;
      *(f32x4a*)op = *(const f32x4a*)(fs + (ns * 16 + m) * 128 + t32 * 4);
    }
  }
}

// ---------------------------------------------------------------------------
extern "C" void kernel_launch(void* const* d_in, const int* in_sizes, int n_in,
                              void* d_out, int out_size, void* d_ws, size_t ws_size,
                              hipStream_t stream) {
  const float* f0    = (const float*)d_in[0];
  const float* f1    = (const float*)d_in[1];
  const float* f2    = (const float*)d_in[2];
  const float* f3    = (const float*)d_in[3];
  const float* mixw  = (const float*)d_in[4];
  const float* iterw = (const float*)d_in[5];
  const float* cg    = (const float*)d_in[6];
  float* out = (float*)d_out;

  // ws (uint16): wtmix 196608 | wtiter 131072 | ccat 4096
  uint16_t* wtmix  = (uint16_t*)d_ws;
  uint16_t* wtiter = wtmix + 196608;
  uint16_t* ccat   = wtiter + 131072;

  k0_prep<<<1296, 256, 0, stream>>>(mixw, iterw, cg, wtmix, wtiter, ccat);
  k_fused<<<2048, 512, 0, stream>>>(f0, f1, f2, f3, wtmix, wtiter, ccat, out);
}

// Round 10
// 871.183 us; speedup vs baseline: 1.1946x; 1.1946x over previous
//
#include <hip/hip_runtime.h>
#include <stdint.h>

// CGIterator on MI355X (gfx950) — block-fused v8: round-9 structure +
// sched_barrier(0) fences after each tile body (anti-hoist: the fully-unrolled
// 10-tile GEMMs let the scheduler hoist ~40 ds_read destinations -> ~220 VGPR
// demand at the 128 cap -> ~500MB/launch scratch spill in rounds 5-9).
// Also: fs epilogue stride 128->132 (4-way bank-conflict fix).
// Stream storage: offset = l*l*NK + (n*(2l+1)+loc)*128 + k, NK = N*K.

#define NK (16384 * 128)

typedef float f32x4 __attribute__((ext_vector_type(4)));
typedef short short8 __attribute__((ext_vector_type(8)));
typedef __bf16 bf16x8 __attribute__((ext_vector_type(8)));

typedef short8 short8a __attribute__((may_alias));
typedef f32x4 f32x4a __attribute__((may_alias));
typedef uint32_t u32a __attribute__((may_alias));
typedef uint16_t u16a __attribute__((may_alias));
typedef float floata __attribute__((may_alias));

__device__ __forceinline__ void sbar() { __builtin_amdgcn_sched_barrier(0); }

__device__ __forceinline__ uint16_t f2b(float f) {   // f32 -> bf16 bits, RNE
  uint32_t u = __builtin_bit_cast(uint32_t, f);
  u += 0x7FFFu + ((u >> 16) & 1u);
  return (uint16_t)(u >> 16);
}
__device__ __forceinline__ float b2f(uint16_t h) {
  uint32_t u = ((uint32_t)h) << 16;
  return __builtin_bit_cast(float, u);
}
__device__ __forceinline__ f32x4 mfma_bf16(short8 a, short8 b, f32x4 c) {
  return __builtin_amdgcn_mfma_f32_16x16x32_bf16(
      __builtin_bit_cast(bf16x8, a), __builtin_bit_cast(bf16x8, b), c, 0, 0, 0);
}
__device__ __forceinline__ int l_of_m(int m) { return (m > 0) + (m > 3) + (m > 8); }
__device__ __forceinline__ int l_of_t(int t) { return (t >= 1) + (t >= 3) + (t >= 6); }

// Tile-row decode. 16-row tiles per l: t0:l0, t1-2:l1, t3-5:l2, t6-9:l3.
// Returns As row index n*16 + m_flat; pad slots clamp to row 0 (real=false).
__device__ __forceinline__ int trow(int t, int ridx, bool& real) {
  const int l = l_of_t(t);
  const int deg = 2 * l + 1;
  const int p0 = (t - (l * (l + 1)) / 2) * 16 + ridx;
  real = p0 < 8 * deg;
  const int p = real ? p0 : 0;
  const int n = p / deg;
  const int mloc = p - n * deg;
  return n * 16 + l * l + mloc;
}

// As byte address with XOR swizzle. row>>3 term matters: l0 rows are n*16,
// so (row&7) alone is constant-0 there.
__device__ __forceinline__ int aswz(int row, int kbyte) {
  return row * 256 + (kbyte ^ (((row ^ (row >> 3)) & 7) << 4));
}

// GEMM, accumulate: acc[t] += A(tile t) @ W_{l(t)}, output col qt*16+r.
// sched_barrier per tile: limits load hoisting -> live set ~90 regs.
__device__ __forceinline__ void gemm_app(const char* AsB, const uint16_t* Wb,
                                         int r, int g, int qt, f32x4* acc) {
#pragma unroll
  for (int lg = 0; lg < 4; ++lg) {
    const uint16_t* Wq = Wb + lg * 16384 + (qt * 16 + r) * 128 + g * 8;
    const short8 w0 = *(const short8a*)(Wq);
    const short8 w1 = *(const short8a*)(Wq + 32);
    const short8 w2 = *(const short8a*)(Wq + 64);
    const short8 w3 = *(const short8a*)(Wq + 96);
#pragma unroll
    for (int u = 0; u <= lg; ++u) {
      const int t = lg * (lg + 1) / 2 + u;
      bool dum;
      const int arow = trow(t, r, dum);
      f32x4 c = acc[t];
      c = mfma_bf16(*(const short8a*)(AsB + aswz(arow, g * 16)), w0, c);
      c = mfma_bf16(*(const short8a*)(AsB + aswz(arow, 64 + g * 16)), w1, c);
      c = mfma_bf16(*(const short8a*)(AsB + aswz(arow, 128 + g * 16)), w2, c);
      c = mfma_bf16(*(const short8a*)(AsB + aswz(arow, 192 + g * 16)), w3, c);
      acc[t] = c;
      sbar();
    }
  }
}

// GEMM, fresh accumulate, write C-frags (bf16) directly to Bs[n][k][m].
__device__ __forceinline__ void gemm_stage_bs(const char* AsB, const uint16_t* Wb,
                                              int r, int g, int qt,
                                              uint16_t* Bs) {
#pragma unroll
  for (int lg = 0; lg < 4; ++lg) {
    const uint16_t* Wq = Wb + lg * 16384 + (qt * 16 + r) * 128 + g * 8;
    const short8 w0 = *(const short8a*)(Wq);
    const short8 w1 = *(const short8a*)(Wq + 32);
    const short8 w2 = *(const short8a*)(Wq + 64);
    const short8 w3 = *(const short8a*)(Wq + 96);
#pragma unroll
    for (int u = 0; u <= lg; ++u) {
      const int t = lg * (lg + 1) / 2 + u;
      bool dum;
      const int arow = trow(t, r, dum);
      f32x4 c = {0.f, 0.f, 0.f, 0.f};
      c = mfma_bf16(*(const short8a*)(AsB + aswz(arow, g * 16)), w0, c);
      c = mfma_bf16(*(const short8a*)(AsB + aswz(arow, 64 + g * 16)), w1, c);
      c = mfma_bf16(*(const short8a*)(AsB + aswz(arow, 128 + g * 16)), w2, c);
      c = mfma_bf16(*(const short8a*)(AsB + aswz(arow, 192 + g * 16)), w3, c);
#pragma unroll
      for (int j = 0; j < 4; ++j) {
        bool cr;
        const int row = trow(t, g * 4 + j, cr);
        if (cr) {
          const int cn = row >> 4, cm = row & 15;
          Bs[cn * 2048 + (qt * 16 + r) * 16 + cm] = f2b(c[j]);
        }
      }
      sbar();
    }
  }
}

// ---------------------------------------------------------------------------
// K0: prep — bf16-transpose weights ([k][q] -> [q][k]) and build Ccat[16][256].
// ---------------------------------------------------------------------------
__global__ __launch_bounds__(256) void k0_prep(
    const float* __restrict__ mixw, const float* __restrict__ iterw,
    const float* __restrict__ cg,
    uint16_t* __restrict__ wtmix, uint16_t* __restrict__ wtiter,
    uint16_t* __restrict__ ccat) {
  int idx = blockIdx.x * 256 + threadIdx.x;
  const int NMIX = 3 * 4 * 16384, NITR = 2 * 4 * 16384;
  if (idx < NMIX) {
    int il = idx >> 14, rem = idx & 16383, q = rem >> 7, k = rem & 127;
    wtmix[idx] = f2b(mixw[il * 16384 + k * 128 + q]);
  } else if (idx < NMIX + NITR) {
    int o = idx - NMIX;
    int tl = o >> 14, rem = o & 16383, q = rem >> 7, k = rem & 127;
    wtiter[o] = f2b(iterw[tl * 16384 + k * 128 + q]);
  } else if (idx < NMIX + NITR + 4096) {
    int o = idx - NMIX - NITR;
    int mg = o >> 8, ij = o & 255, ig = ij >> 4, jg = ij & 15;
    int l = l_of_m(mg), m = mg - l * l;
    int l1 = l_of_m(ig), i = ig - l1 * l1;
    int l2 = l_of_m(jg), j = jg - l2 * l2;
    ccat[o] = f2b(cg[(l1 * 16 + l2 * 4 + l) * 343 + i * 49 + j * 7 + m]);
  }
}

// ---------------------------------------------------------------------------
// Fused block kernel: 512 threads = 8 waves; wave w owns channel tile qt=w
// for GEMMs and row n=w for the TP.
// LDS 96KB: As [128 row][128 k] bf16 swizzled | Bs [8 n][128 k][16 m] (mixed1)
// | B2s same (mixed2). Final f32 [128][132] staging overlays As+Bs.
// ---------------------------------------------------------------------------
__global__ __launch_bounds__(512) void k_fused(
    const float* __restrict__ f0, const float* __restrict__ f1,
    const float* __restrict__ f2, const float* __restrict__ f3,
    const uint16_t* __restrict__ wtmix, const uint16_t* __restrict__ wtiter,
    const uint16_t* __restrict__ ccat, float* __restrict__ out) {
  __shared__ __align__(16) uint16_t smem[49152];   // 96KB
  char* const AsB = (char*)smem;        // swizzled [128 row][128 k] bf16
  uint16_t* const Bs = smem + 16384;    // mixed1: Bs[n*2048 + k*16 + m]
  uint16_t* const B2s = smem + 32768;   // mixed2: same layout

  const int tid = threadIdx.x;
  const int lane = tid & 63, wid = tid >> 6;
  const int g = lane >> 4, r = lane & 15;
  const int qt = wid;
  const int nblk = blockIdx.x * 8;

  // zero all LDS (coverage insurance)
  {
    u32a* z = (u32a*)smem;
    for (int i = 0; i < 48; ++i) z[tid + i * 512] = 0;
  }
  __syncthreads();

  // ---- phase 0: stage feats (bf16) into As ----
  for (int i = 0; i < 32; ++i) {
    const int elem = tid + i * 512;
    const int row = elem >> 7, k = elem & 127;
    const int nn = row >> 4, mf = row & 15;
    const int l = l_of_m(mf), loc = mf - l * l;
    const float* F = (l == 0) ? f0 : (l == 1) ? f1 : (l == 2) ? f2 : f3;
    *(u16a*)(AsB + aswz(row, k * 2)) =
        f2b(F[((size_t)(nblk + nn) * (2 * l + 1) + loc) * 128 + k]);
  }
  __syncthreads();

  // ---- mixing: cur = feats@W0 (f32 regs), mixed1 -> Bs, mixed2 -> B2s ----
  f32x4 cur[10];
#pragma unroll
  for (int t = 0; t < 10; ++t) cur[t] = f32x4{0.f, 0.f, 0.f, 0.f};
  gemm_app(AsB, wtmix, r, g, qt, cur);
  gemm_stage_bs(AsB, wtmix + 4 * 16384, r, g, qt, Bs);
  gemm_stage_bs(AsB, wtmix + 8 * 16384, r, g, qt, B2s);
  __syncthreads();   // feats reads done; As may be overwritten

  const int ih = g >> 1, jb = (g & 1) * 8;

#pragma unroll 1
  for (int it = 0; it < 2; ++it) {
    const uint16_t* Bx = (it == 0) ? Bs : B2s;
    // ---- stage cur -> As (bf16) ----
#pragma unroll
    for (int t = 0; t < 10; ++t)
#pragma unroll
      for (int j = 0; j < 4; ++j) {
        bool cr;
        const int row = trow(t, g * 4 + j, cr);
        if (cr) *(u16a*)(AsB + aswz(row, (qt * 16 + r) * 2)) = f2b(cur[t][j]);
      }
    __syncthreads();

    // ---- TP for n = wid: tacc = Ccat(16x256) @ P(256x128), P in-register ----
    f32x4 tacc[8];
#pragma unroll
    for (int ki = 0; ki < 8; ++ki) tacc[ki] = f32x4{0.f, 0.f, 0.f, 0.f};
#pragma unroll
    for (int cc = 0; cc < 8; ++cc) {
      const short8 cfr = *(const short8a*)(ccat + r * 256 + cc * 32 + g * 8);
      const int arow = wid * 16 + cc * 2 + ih;
#pragma unroll
      for (int ki = 0; ki < 8; ++ki) {
        const int k = ki * 16 + r;
        const float av = b2f(*(const u16a*)(AsB + aswz(arow, k * 2)));
        const short8 bv = *(const short8a*)&Bx[wid * 2048 + k * 16 + jb];
        short8 pv;
#pragma unroll
        for (int e = 0; e < 8; ++e)
          pv[e] = (short)f2b(av * b2f((uint16_t)bv[e]));
        tacc[ki] = mfma_bf16(cfr, pv, tacc[ki]);
      }
      sbar();
    }
    __syncthreads();   // all As reads complete before tp overwrite

    // ---- tp -> As rows of n = wid ----
#pragma unroll
    for (int ki = 0; ki < 8; ++ki)
#pragma unroll
      for (int j = 0; j < 4; ++j)
        *(u16a*)(AsB + aswz(wid * 16 + g * 4 + j, (ki * 16 + r) * 2)) =
            f2b(tacc[ki][j]);
    __syncthreads();

    // ---- cur += tp @ iter_w[it] ----
    gemm_app(AsB, wtiter + it * 4 * 16384, r, g, qt, cur);
    __syncthreads();
  }

  // ---- final: stage f32 in LDS (overlay, stride 132), coalesced store ----
  floata* fs = (floata*)smem;   // [128 row][132] f32 = 67.6KB (< 96KB)
#pragma unroll
  for (int t = 0; t < 10; ++t)
#pragma unroll
    for (int j = 0; j < 4; ++j) {
      bool cr;
      const int row = trow(t, g * 4 + j, cr);
      if (cr) fs[row * 132 + qt * 16 + r] = cur[t][j];
    }
  __syncthreads();
  {
    const int grp = tid >> 5, t32 = tid & 31;
    const int ns = grp >> 1, mh = (grp & 1) * 8;
    for (int m8 = 0; m8 < 8; ++m8) {
      const int m = mh + m8;
      const int l = l_of_m(m), loc = m - l * l;
      float* op = out + (size_t)l * l * NK +
                  ((size_t)(nblk + ns) * (2 * l + 1) + loc) * 128 + t32 * 4;
      *(f32x4a*)op = *(const f32x4a*)(fs + (ns * 16 + m) * 132 + t32 * 4);
    }
  }
}

// ---------------------------------------------------------------------------
extern "C" void kernel_launch(void* const* d_in, const int* in_sizes, int n_in,
                              void* d_out, int out_size, void* d_ws, size_t ws_size,
                              hipStream_t stream) {
  const float* f0    = (const float*)d_in[0];
  const float* f1    = (const float*)d_in[1];
  const float* f2    = (const float*)d_in[2];
  const float* f3    = (const float*)d_in[3];
  const float* mixw  = (const float*)d_in[4];
  const float* iterw = (const float*)d_in[5];
  const float* cg    = (const float*)d_in[6];
  float* out = (float*)d_out;

  // ws (uint16): wtmix 196608 | wtiter 131072 | ccat 4096
  uint16_t* wtmix  = (uint16_t*)d_ws;
  uint16_t* wtiter = wtmix + 196608;
  uint16_t* ccat   = wtiter + 131072;

  k0_prep<<<1296, 256, 0, stream>>>(mixw, iterw, cg, wtmix, wtiter, ccat);
  k_fused<<<2048, 512, 0, stream>>>(f0, f1, f2, f3, wtmix, wtiter, ccat, out);
}

// Round 12
// 843.189 us; speedup vs baseline: 1.2343x; 1.0332x over previous
//
#include <hip/hip_runtime.h>
#include <stdint.h>

// CGIterator on MI355X (gfx950) — block-fused v9b: 16-wave (1024-thread) block
// owns 8 rows n. Per-wave state halved vs v8 (cur[5]+tacc[4]) -> fits the
// 128-VGPR cap without spill. Wave w: GEMM tile-half th=w>>3 at column qt=w&7;
// TP row n=w&7, ki-half kh=w>>3. LDS 96KB -> 1 block/CU, 16 waves/CU.
// v9 bug fixed: final-store loop trip count 16 -> 4 (1024 threads x 4 f32x4
// = 4096 = 128x128/4; the 16 was copied from the 512-thread version -> OOB).
// Stream storage: offset = l*l*NK + (n*(2l+1)+loc)*128 + k, NK = N*K.

#define NK (16384 * 128)

typedef float f32x4 __attribute__((ext_vector_type(4)));
typedef short short8 __attribute__((ext_vector_type(8)));
typedef __bf16 bf16x8 __attribute__((ext_vector_type(8)));

typedef short8 short8a __attribute__((may_alias));
typedef f32x4 f32x4a __attribute__((may_alias));
typedef uint32_t u32a __attribute__((may_alias));
typedef uint16_t u16a __attribute__((may_alias));
typedef float floata __attribute__((may_alias));

__device__ __forceinline__ void sbar() { __builtin_amdgcn_sched_barrier(0); }

__device__ __forceinline__ uint16_t f2b(float f) {   // f32 -> bf16 bits, RNE
  uint32_t u = __builtin_bit_cast(uint32_t, f);
  u += 0x7FFFu + ((u >> 16) & 1u);
  return (uint16_t)(u >> 16);
}
__device__ __forceinline__ float b2f(uint16_t h) {
  uint32_t u = ((uint32_t)h) << 16;
  return __builtin_bit_cast(float, u);
}
__device__ __forceinline__ f32x4 mfma_bf16(short8 a, short8 b, f32x4 c) {
  return __builtin_amdgcn_mfma_f32_16x16x32_bf16(
      __builtin_bit_cast(bf16x8, a), __builtin_bit_cast(bf16x8, b), c, 0, 0, 0);
}
__device__ __forceinline__ int l_of_m(int m) { return (m > 0) + (m > 3) + (m > 8); }
__device__ __forceinline__ int l_of_t(int t) { return (t >= 1) + (t >= 3) + (t >= 6); }

// Tile-row decode. 16-row tiles per l: t0:l0, t1-2:l1, t3-5:l2, t6-9:l3.
// Returns As row index n*16 + m_flat; pad slots clamp to row 0 (real=false).
__device__ __forceinline__ int trow(int t, int ridx, bool& real) {
  const int l = l_of_t(t);
  const int deg = 2 * l + 1;
  const int p0 = (t - (l * (l + 1)) / 2) * 16 + ridx;
  real = p0 < 8 * deg;
  const int p = real ? p0 : 0;
  const int n = p / deg;
  const int mloc = p - n * deg;
  return n * 16 + l * l + mloc;
}

// As byte address with XOR swizzle. row>>3 term matters: l0 rows are n*16,
// so (row&7) alone is constant-0 there.
__device__ __forceinline__ int aswz(int row, int kbyte) {
  return row * 256 + (kbyte ^ (((row ^ (row >> 3)) & 7) << 4));
}

// GEMM over the wave's 5-tile half: acc[i] += A(tile th*5+i) @ W_{l(t)},
// output col qt*16+r. sched_barrier per tile caps load hoisting.
__device__ __forceinline__ void gemm_app(const char* AsB, const uint16_t* Wb,
                                         int r, int g, int qt, int th,
                                         f32x4* acc) {
#pragma unroll
  for (int i = 0; i < 5; ++i) {
    const int t = th * 5 + i;
    const int lt = l_of_t(t);
    bool dum;
    const int arow = trow(t, r, dum);
    const uint16_t* Wq = Wb + lt * 16384 + (qt * 16 + r) * 128 + g * 8;
    f32x4 c = acc[i];
    c = mfma_bf16(*(const short8a*)(AsB + aswz(arow, g * 16)),
                  *(const short8a*)(Wq), c);
    c = mfma_bf16(*(const short8a*)(AsB + aswz(arow, 64 + g * 16)),
                  *(const short8a*)(Wq + 32), c);
    c = mfma_bf16(*(const short8a*)(AsB + aswz(arow, 128 + g * 16)),
                  *(const short8a*)(Wq + 64), c);
    c = mfma_bf16(*(const short8a*)(AsB + aswz(arow, 192 + g * 16)),
                  *(const short8a*)(Wq + 96), c);
    acc[i] = c;
    sbar();
  }
}

// GEMM over the wave's 5-tile half, fresh accumulate, C-frags -> Bs[n][k][m].
__device__ __forceinline__ void gemm_stage_bs(const char* AsB,
                                              const uint16_t* Wb, int r, int g,
                                              int qt, int th, uint16_t* Bs) {
#pragma unroll
  for (int i = 0; i < 5; ++i) {
    const int t = th * 5 + i;
    const int lt = l_of_t(t);
    bool dum;
    const int arow = trow(t, r, dum);
    const uint16_t* Wq = Wb + lt * 16384 + (qt * 16 + r) * 128 + g * 8;
    f32x4 c = {0.f, 0.f, 0.f, 0.f};
    c = mfma_bf16(*(const short8a*)(AsB + aswz(arow, g * 16)),
                  *(const short8a*)(Wq), c);
    c = mfma_bf16(*(const short8a*)(AsB + aswz(arow, 64 + g * 16)),
                  *(const short8a*)(Wq + 32), c);
    c = mfma_bf16(*(const short8a*)(AsB + aswz(arow, 128 + g * 16)),
                  *(const short8a*)(Wq + 64), c);
    c = mfma_bf16(*(const short8a*)(AsB + aswz(arow, 192 + g * 16)),
                  *(const short8a*)(Wq + 96), c);
#pragma unroll
    for (int j = 0; j < 4; ++j) {
      bool cr;
      const int row = trow(t, g * 4 + j, cr);
      if (cr) {
        const int cn = row >> 4, cm = row & 15;
        Bs[cn * 2048 + (qt * 16 + r) * 16 + cm] = f2b(c[j]);
      }
    }
    sbar();
  }
}

// ---------------------------------------------------------------------------
// K0: prep — bf16-transpose weights ([k][q] -> [q][k]) and build Ccat[16][256].
// ---------------------------------------------------------------------------
__global__ __launch_bounds__(256) void k0_prep(
    const float* __restrict__ mixw, const float* __restrict__ iterw,
    const float* __restrict__ cg,
    uint16_t* __restrict__ wtmix, uint16_t* __restrict__ wtiter,
    uint16_t* __restrict__ ccat) {
  int idx = blockIdx.x * 256 + threadIdx.x;
  const int NMIX = 3 * 4 * 16384, NITR = 2 * 4 * 16384;
  if (idx < NMIX) {
    int il = idx >> 14, rem = idx & 16383, q = rem >> 7, k = rem & 127;
    wtmix[idx] = f2b(mixw[il * 16384 + k * 128 + q]);
  } else if (idx < NMIX + NITR) {
    int o = idx - NMIX;
    int tl = o >> 14, rem = o & 16383, q = rem >> 7, k = rem & 127;
    wtiter[o] = f2b(iterw[tl * 16384 + k * 128 + q]);
  } else if (idx < NMIX + NITR + 4096) {
    int o = idx - NMIX - NITR;
    int mg = o >> 8, ij = o & 255, ig = ij >> 4, jg = ij & 15;
    int l = l_of_m(mg), m = mg - l * l;
    int l1 = l_of_m(ig), i = ig - l1 * l1;
    int l2 = l_of_m(jg), j = jg - l2 * l2;
    ccat[o] = f2b(cg[(l1 * 16 + l2 * 4 + l) * 343 + i * 49 + j * 7 + m]);
  }
}

// ---------------------------------------------------------------------------
// Fused block kernel: 1024 threads = 16 waves.
// LDS 96KB: As [128 row][128 k] bf16 swizzled | Bs [8 n][128 k][16 m] (mixed1)
// | B2s same (mixed2). Final f32 [128][132] staging overlays As+Bs.
// ---------------------------------------------------------------------------
__global__ __launch_bounds__(1024) void k_fused(
    const float* __restrict__ f0, const float* __restrict__ f1,
    const float* __restrict__ f2, const float* __restrict__ f3,
    const uint16_t* __restrict__ wtmix, const uint16_t* __restrict__ wtiter,
    const uint16_t* __restrict__ ccat, float* __restrict__ out) {
  __shared__ __align__(16) uint16_t smem[49152];   // 96KB
  char* const AsB = (char*)smem;        // swizzled [128 row][128 k] bf16
  uint16_t* const Bs = smem + 16384;    // mixed1: Bs[n*2048 + k*16 + m]
  uint16_t* const B2s = smem + 32768;   // mixed2: same layout

  const int tid = threadIdx.x;
  const int lane = tid & 63, wid = tid >> 6;       // wid in [0,16)
  const int g = lane >> 4, r = lane & 15;
  const int qt = wid & 7;                          // GEMM output-column tile
  const int th = wid >> 3;                         // GEMM tile half (0/1)
  const int ntp = wid & 7;                         // TP row n
  const int kh = wid >> 3;                         // TP ki half (0/1)
  const int nblk = blockIdx.x * 8;

  // zero all LDS (coverage insurance)
  {
    u32a* z = (u32a*)smem;
    for (int i = 0; i < 24; ++i) z[tid + i * 1024] = 0;
  }
  __syncthreads();

  // ---- phase 0: stage feats (bf16) into As ----
  for (int i = 0; i < 16; ++i) {
    const int elem = tid + i * 1024;
    const int row = elem >> 7, k = elem & 127;
    const int nn = row >> 4, mf = row & 15;
    const int l = l_of_m(mf), loc = mf - l * l;
    const float* F = (l == 0) ? f0 : (l == 1) ? f1 : (l == 2) ? f2 : f3;
    *(u16a*)(AsB + aswz(row, k * 2)) =
        f2b(F[((size_t)(nblk + nn) * (2 * l + 1) + loc) * 128 + k]);
  }
  __syncthreads();

  // ---- mixing: cur = feats@W0 (f32 regs), mixed1 -> Bs, mixed2 -> B2s ----
  f32x4 cur[5];
#pragma unroll
  for (int i = 0; i < 5; ++i) cur[i] = f32x4{0.f, 0.f, 0.f, 0.f};
  gemm_app(AsB, wtmix, r, g, qt, th, cur);
  gemm_stage_bs(AsB, wtmix + 4 * 16384, r, g, qt, th, Bs);
  gemm_stage_bs(AsB, wtmix + 8 * 16384, r, g, qt, th, B2s);
  __syncthreads();   // feats reads done; As may be overwritten

  const int ih = g >> 1, jb = (g & 1) * 8;

#pragma unroll 1
  for (int it = 0; it < 2; ++it) {
    const uint16_t* Bx = (it == 0) ? Bs : B2s;
    // ---- stage cur -> As (bf16), wave's 5 tiles at column qt ----
#pragma unroll
    for (int i = 0; i < 5; ++i) {
      const int t = th * 5 + i;
#pragma unroll
      for (int j = 0; j < 4; ++j) {
        bool cr;
        const int row = trow(t, g * 4 + j, cr);
        if (cr) *(u16a*)(AsB + aswz(row, (qt * 16 + r) * 2)) = f2b(cur[i][j]);
      }
    }
    __syncthreads();

    // ---- TP for n = ntp, ki half kh: tacc = Ccat @ P, P in-register ----
    f32x4 tacc[4];
#pragma unroll
    for (int q = 0; q < 4; ++q) tacc[q] = f32x4{0.f, 0.f, 0.f, 0.f};
#pragma unroll
    for (int cc = 0; cc < 8; ++cc) {
      const short8 cfr = *(const short8a*)(ccat + r * 256 + cc * 32 + g * 8);
      const int arow = ntp * 16 + cc * 2 + ih;
#pragma unroll
      for (int q = 0; q < 4; ++q) {
        const int k = (kh * 4 + q) * 16 + r;
        const float av = b2f(*(const u16a*)(AsB + aswz(arow, k * 2)));
        const short8 bv = *(const short8a*)&Bx[ntp * 2048 + k * 16 + jb];
        short8 pv;
#pragma unroll
        for (int e = 0; e < 8; ++e)
          pv[e] = (short)f2b(av * b2f((uint16_t)bv[e]));
        tacc[q] = mfma_bf16(cfr, pv, tacc[q]);
      }
      sbar();
    }
    __syncthreads();   // all As reads complete before tp overwrite

    // ---- tp -> As rows of n = ntp, ki half kh ----
#pragma unroll
    for (int q = 0; q < 4; ++q)
#pragma unroll
      for (int j = 0; j < 4; ++j)
        *(u16a*)(AsB +
                 aswz(ntp * 16 + g * 4 + j, ((kh * 4 + q) * 16 + r) * 2)) =
            f2b(tacc[q][j]);
    __syncthreads();

    // ---- cur += tp @ iter_w[it] ----
    gemm_app(AsB, wtiter + it * 4 * 16384, r, g, qt, th, cur);
    __syncthreads();
  }

  // ---- final: stage f32 in LDS (overlay, stride 132), coalesced store ----
  floata* fs = (floata*)smem;   // [128 row][132] f32 = 67.6KB (< 96KB)
#pragma unroll
  for (int i = 0; i < 5; ++i) {
    const int t = th * 5 + i;
#pragma unroll
    for (int j = 0; j < 4; ++j) {
      bool cr;
      const int row = trow(t, g * 4 + j, cr);
      if (cr) fs[row * 132 + qt * 16 + r] = cur[i][j];
    }
  }
  __syncthreads();
  for (int i = 0; i < 4; ++i) {                // 4096 f32x4 / 1024 threads
    const int flat4 = tid + i * 1024;          // f32x4 index
    const int row = flat4 >> 5, k = (flat4 & 31) * 4;
    const int nn = row >> 4, mf = row & 15;
    const int l = l_of_m(mf), loc = mf - l * l;
    float* op = out + (size_t)l * l * NK +
                ((size_t)(nblk + nn) * (2 * l + 1) + loc) * 128 + k;
    *(f32x4a*)op = *(const f32x4a*)(fs + row * 132 + k);
  }
}

// ---------------------------------------------------------------------------
extern "C" void kernel_launch(void* const* d_in, const int* in_sizes, int n_in,
                              void* d_out, int out_size, void* d_ws, size_t ws_size,
                              hipStream_t stream) {
  const float* f0    = (const float*)d_in[0];
  const float* f1    = (const float*)d_in[1];
  const float* f2    = (const float*)d_in[2];
  const float* f3    = (const float*)d_in[3];
  const float* mixw  = (const float*)d_in[4];
  const float* iterw = (const float*)d_in[5];
  const float* cg    = (const float*)d_in[6];
  float* out = (float*)d_out;

  // ws (uint16): wtmix 196608 | wtiter 131072 | ccat 4096
  uint16_t* wtmix  = (uint16_t*)d_ws;
  uint16_t* wtiter = wtmix + 196608;
  uint16_t* ccat   = wtiter + 131072;

  k0_prep<<<1296, 256, 0, stream>>>(mixw, iterw, cg, wtmix, wtiter, ccat);
  k_fused<<<2048, 1024, 0, stream>>>(f0, f1, f2, f3, wtmix, wtiter, ccat, out);
}

// Round 13
// 718.746 us; speedup vs baseline: 1.4480x; 1.1731x over previous
//
#include <hip/hip_runtime.h>
#include <stdint.h>

// CGIterator on MI355X (gfx950) — block-fused v10: accumulator-in-LDS.
// Lesson of r5-r12: the register budget is allocator-controlled (128/64) and
// any persistent per-wave accumulator state spills (~0.5-1.3GB/launch scratch).
// v10 keeps `cur` in LDS f32 (Cf32, 64KB, XOR-swizzled); every GEMM is
// fresh-accumulate -> guarded RMW into Cf32. Transient live set ~55 VGPRs.
// mixed2 buffer eliminated by re-staging feats in iter 1 (L3-warm re-read).
// LDS 128KB: As 32KB (feats/tp bf16 swz) | Cf32 64KB | Bs 32KB (mixed, swz).
// 1024 threads = 16 waves; wave w: GEMM tiles th*5+i at col qt (th=w>>3,
// qt=w&7); TP row n=w&7, ki-half kh=w>>3.
// Stream storage: offset = l*l*NK + (n*(2l+1)+loc)*128 + k, NK = N*K.

#define NK (16384 * 128)

typedef float f32x4 __attribute__((ext_vector_type(4)));
typedef short short8 __attribute__((ext_vector_type(8)));
typedef __bf16 bf16x8 __attribute__((ext_vector_type(8)));

typedef short8 short8a __attribute__((may_alias));
typedef f32x4 f32x4a __attribute__((may_alias));
typedef uint32_t u32a __attribute__((may_alias));
typedef uint16_t u16a __attribute__((may_alias));
typedef float floata __attribute__((may_alias));

__device__ __forceinline__ void sbar() { __builtin_amdgcn_sched_barrier(0); }

__device__ __forceinline__ uint16_t f2b(float f) {   // f32 -> bf16 bits, RNE
  uint32_t u = __builtin_bit_cast(uint32_t, f);
  u += 0x7FFFu + ((u >> 16) & 1u);
  return (uint16_t)(u >> 16);
}
__device__ __forceinline__ float b2f(uint16_t h) {
  uint32_t u = ((uint32_t)h) << 16;
  return __builtin_bit_cast(float, u);
}
__device__ __forceinline__ f32x4 mfma_bf16(short8 a, short8 b, f32x4 c) {
  return __builtin_amdgcn_mfma_f32_16x16x32_bf16(
      __builtin_bit_cast(bf16x8, a), __builtin_bit_cast(bf16x8, b), c, 0, 0, 0);
}
__device__ __forceinline__ int l_of_m(int m) { return (m > 0) + (m > 3) + (m > 8); }
__device__ __forceinline__ int l_of_t(int t) { return (t >= 1) + (t >= 3) + (t >= 6); }

// Tile-row decode. 16-row tiles per l: t0:l0, t1-2:l1, t3-5:l2, t6-9:l3.
// Returns As row index n*16 + m_flat; pad slots clamp to row 0 (real=false).
__device__ __forceinline__ int trow(int t, int ridx, bool& real) {
  const int l = l_of_t(t);
  const int deg = 2 * l + 1;
  const int p0 = (t - (l * (l + 1)) / 2) * 16 + ridx;
  real = p0 < 8 * deg;
  const int p = real ? p0 : 0;
  const int n = p / deg;
  const int mloc = p - n * deg;
  return n * 16 + l * l + mloc;
}

// As (bf16) byte address, XOR-swizzled. row>>3 term: l0 rows are n*16.
__device__ __forceinline__ int aswz(int row, int kbyte) {
  return row * 256 + (kbyte ^ (((row ^ (row >> 3)) & 7) << 4));
}
// Cf32 (f32) byte address, XOR-swizzled (16B granule within 512B row).
__device__ __forceinline__ int cswz(int row, int colbyte) {
  return row * 512 + (colbyte ^ (((row ^ (row >> 3)) & 7) << 4));
}
// Bs (bf16 [8 n][128 k][16 m]) byte address, XOR-swizzled on k.
__device__ __forceinline__ int bswz(int n, int k, int m) {
  return n * 4096 + ((k * 32 + m * 2) ^ ((k & 7) << 4));
}

// GEMM over the wave's 5-tile half, fresh accumulate, then RMW into Cf32.
// ASSIGN=1: Cf32 = c (mixing); ASSIGN=0: Cf32 += c (iteration linear).
template <int ASSIGN>
__device__ __forceinline__ void gemm_c(const char* AsB, const uint16_t* Wb,
                                       char* Cb, int r, int g, int qt, int th) {
#pragma unroll
  for (int i = 0; i < 5; ++i) {
    const int t = th * 5 + i;
    const int lt = l_of_t(t);
    bool dum;
    const int arow = trow(t, r, dum);
    const uint16_t* Wq = Wb + lt * 16384 + (qt * 16 + r) * 128 + g * 8;
    f32x4 c = {0.f, 0.f, 0.f, 0.f};
    c = mfma_bf16(*(const short8a*)(AsB + aswz(arow, g * 16)),
                  *(const short8a*)(Wq), c);
    c = mfma_bf16(*(const short8a*)(AsB + aswz(arow, 64 + g * 16)),
                  *(const short8a*)(Wq + 32), c);
    c = mfma_bf16(*(const short8a*)(AsB + aswz(arow, 128 + g * 16)),
                  *(const short8a*)(Wq + 64), c);
    c = mfma_bf16(*(const short8a*)(AsB + aswz(arow, 192 + g * 16)),
                  *(const short8a*)(Wq + 96), c);
#pragma unroll
    for (int j = 0; j < 4; ++j) {
      bool cr;
      const int row = trow(t, g * 4 + j, cr);
      if (cr) {
        floata* p = (floata*)(Cb + cswz(row, (qt * 16 + r) * 4));
        *p = ASSIGN ? c[j] : (*p + c[j]);
      }
    }
    sbar();
  }
}

// GEMM over the wave's 5-tile half, fresh accumulate, C-frags -> Bs (swizzled).
__device__ __forceinline__ void gemm_bs(const char* AsB, const uint16_t* Wb,
                                        char* BsB, int r, int g, int qt, int th) {
#pragma unroll
  for (int i = 0; i < 5; ++i) {
    const int t = th * 5 + i;
    const int lt = l_of_t(t);
    bool dum;
    const int arow = trow(t, r, dum);
    const uint16_t* Wq = Wb + lt * 16384 + (qt * 16 + r) * 128 + g * 8;
    f32x4 c = {0.f, 0.f, 0.f, 0.f};
    c = mfma_bf16(*(const short8a*)(AsB + aswz(arow, g * 16)),
                  *(const short8a*)(Wq), c);
    c = mfma_bf16(*(const short8a*)(AsB + aswz(arow, 64 + g * 16)),
                  *(const short8a*)(Wq + 32), c);
    c = mfma_bf16(*(const short8a*)(AsB + aswz(arow, 128 + g * 16)),
                  *(const short8a*)(Wq + 64), c);
    c = mfma_bf16(*(const short8a*)(AsB + aswz(arow, 192 + g * 16)),
                  *(const short8a*)(Wq + 96), c);
#pragma unroll
    for (int j = 0; j < 4; ++j) {
      bool cr;
      const int row = trow(t, g * 4 + j, cr);
      if (cr) {
        const int cn = row >> 4, cm = row & 15;
        *(u16a*)(BsB + bswz(cn, qt * 16 + r, cm)) = f2b(c[j]);
      }
    }
    sbar();
  }
}

// TP for row n=ntp, ki-half kh: tacc = Ccat @ P (P built in-register from
// Cf32 (f32 av) x Bs (bf16)); writes tp into As (bf16, swizzled).
__device__ __forceinline__ void tp_half(char* AsB, const char* Cb,
                                        const char* BsB,
                                        const uint16_t* ccat, int ntp, int kh,
                                        int r, int g) {
  const int ih = g >> 1, jb = (g & 1) * 8;
  f32x4 tacc[4];
#pragma unroll
  for (int q = 0; q < 4; ++q) tacc[q] = f32x4{0.f, 0.f, 0.f, 0.f};
#pragma unroll
  for (int cc = 0; cc < 8; ++cc) {
    const short8 cfr = *(const short8a*)(ccat + r * 256 + cc * 32 + g * 8);
    const int arow = ntp * 16 + cc * 2 + ih;
#pragma unroll
    for (int q = 0; q < 4; ++q) {
      const int k = (kh * 4 + q) * 16 + r;
      const float av = *(const floata*)(Cb + cswz(arow, k * 4));
      const short8 bv = *(const short8a*)(BsB + bswz(ntp, k, jb));
      short8 pv;
#pragma unroll
      for (int e = 0; e < 8; ++e)
        pv[e] = (short)f2b(av * b2f((uint16_t)bv[e]));
      tacc[q] = mfma_bf16(cfr, pv, tacc[q]);
    }
    sbar();
  }
#pragma unroll
  for (int q = 0; q < 4; ++q)
#pragma unroll
    for (int j = 0; j < 4; ++j)
      *(u16a*)(AsB + aswz(ntp * 16 + g * 4 + j, ((kh * 4 + q) * 16 + r) * 2)) =
          f2b(tacc[q][j]);
}

// ---------------------------------------------------------------------------
// K0: prep — bf16-transpose weights ([k][q] -> [q][k]) and build Ccat[16][256].
// ---------------------------------------------------------------------------
__global__ __launch_bounds__(256) void k0_prep(
    const float* __restrict__ mixw, const float* __restrict__ iterw,
    const float* __restrict__ cg,
    uint16_t* __restrict__ wtmix, uint16_t* __restrict__ wtiter,
    uint16_t* __restrict__ ccat) {
  int idx = blockIdx.x * 256 + threadIdx.x;
  const int NMIX = 3 * 4 * 16384, NITR = 2 * 4 * 16384;
  if (idx < NMIX) {
    int il = idx >> 14, rem = idx & 16383, q = rem >> 7, k = rem & 127;
    wtmix[idx] = f2b(mixw[il * 16384 + k * 128 + q]);
  } else if (idx < NMIX + NITR) {
    int o = idx - NMIX;
    int tl = o >> 14, rem = o & 16383, q = rem >> 7, k = rem & 127;
    wtiter[o] = f2b(iterw[tl * 16384 + k * 128 + q]);
  } else if (idx < NMIX + NITR + 4096) {
    int o = idx - NMIX - NITR;
    int mg = o >> 8, ij = o & 255, ig = ij >> 4, jg = ij & 15;
    int l = l_of_m(mg), m = mg - l * l;
    int l1 = l_of_m(ig), i = ig - l1 * l1;
    int l2 = l_of_m(jg), j = jg - l2 * l2;
    ccat[o] = f2b(cg[(l1 * 16 + l2 * 4 + l) * 343 + i * 49 + j * 7 + m]);
  }
}

// ---------------------------------------------------------------------------
// Fused block kernel: 1024 threads = 16 waves, 8 rows n per block.
// ---------------------------------------------------------------------------
__global__ __launch_bounds__(1024) void k_fused(
    const float* __restrict__ f0, const float* __restrict__ f1,
    const float* __restrict__ f2, const float* __restrict__ f3,
    const uint16_t* __restrict__ wtmix, const uint16_t* __restrict__ wtiter,
    const uint16_t* __restrict__ ccat, float* __restrict__ out) {
  __shared__ __align__(16) char smem[131072];   // 128KB
  char* const AsB = smem;                 // 32KB bf16 [128][128] swizzled
  char* const Cb = smem + 32768;          // 64KB f32  [128][128] swizzled
  char* const BsB = smem + 98304;         // 32KB bf16 [8][128][16] swizzled

  const int tid = threadIdx.x;
  const int lane = tid & 63, wid = tid >> 6;       // wid in [0,16)
  const int g = lane >> 4, r = lane & 15;
  const int qt = wid & 7;                          // GEMM output-column tile
  const int th = wid >> 3;                         // GEMM tile half (0/1)
  const int ntp = wid & 7;                         // TP row n
  const int kh = wid >> 3;                         // TP ki half (0/1)
  const int nblk = blockIdx.x * 8;

  // zero all LDS (coverage insurance)
  {
    u32a* z = (u32a*)smem;
    for (int i = 0; i < 32; ++i) z[tid + i * 1024] = 0;
  }
  __syncthreads();

  // ---- stage feats (bf16) into As ----
  auto stage_feats = [&]() {
    for (int i = 0; i < 16; ++i) {
      const int elem = tid + i * 1024;
      const int row = elem >> 7, k = elem & 127;
      const int nn = row >> 4, mf = row & 15;
      const int l = l_of_m(mf), loc = mf - l * l;
      const float* F = (l == 0) ? f0 : (l == 1) ? f1 : (l == 2) ? f2 : f3;
      *(u16a*)(AsB + aswz(row, k * 2)) =
          f2b(F[((size_t)(nblk + nn) * (2 * l + 1) + loc) * 128 + k]);
    }
  };

  stage_feats();
  __syncthreads();

  // ---- mixing: Cf32 = feats@W0, Bs = feats@W1 ----
  gemm_c<1>(AsB, wtmix, Cb, r, g, qt, th);
  gemm_bs(AsB, wtmix + 4 * 16384, BsB, r, g, qt, th);
  __syncthreads();

  // ---- iteration 0: TP(cur, mixed1) -> As; Cf32 += tp @ iter_w[0] ----
  tp_half(AsB, Cb, BsB, ccat, ntp, kh, r, g);   // overwrites As (feats dead)
  __syncthreads();
  gemm_c<0>(AsB, wtiter, Cb, r, g, qt, th);
  __syncthreads();

  // ---- iteration 1: re-stage feats, Bs = feats@W2, TP, linear ----
  stage_feats();                                 // overwrites As (tp dead)
  __syncthreads();
  gemm_bs(AsB, wtmix + 8 * 16384, BsB, r, g, qt, th);
  __syncthreads();
  tp_half(AsB, Cb, BsB, ccat, ntp, kh, r, g);   // overwrites As
  __syncthreads();
  gemm_c<0>(AsB, wtiter + 4 * 16384, Cb, r, g, qt, th);
  __syncthreads();

  // ---- final: coalesced store straight from Cf32 ----
  for (int i = 0; i < 4; ++i) {                // 4096 f32x4 / 1024 threads
    const int flat4 = tid + i * 1024;
    const int row = flat4 >> 5, k = (flat4 & 31) * 4;
    const int nn = row >> 4, mf = row & 15;
    const int l = l_of_m(mf), loc = mf - l * l;
    float* op = out + (size_t)l * l * NK +
                ((size_t)(nblk + nn) * (2 * l + 1) + loc) * 128 + k;
    *(f32x4a*)op = *(const f32x4a*)(Cb + cswz(row, k * 4));
  }
}

// ---------------------------------------------------------------------------
extern "C" void kernel_launch(void* const* d_in, const int* in_sizes, int n_in,
                              void* d_out, int out_size, void* d_ws, size_t ws_size,
                              hipStream_t stream) {
  const float* f0    = (const float*)d_in[0];
  const float* f1    = (const float*)d_in[1];
  const float* f2    = (const float*)d_in[2];
  const float* f3    = (const float*)d_in[3];
  const float* mixw  = (const float*)d_in[4];
  const float* iterw = (const float*)d_in[5];
  const float* cg    = (const float*)d_in[6];
  float* out = (float*)d_out;

  // ws (uint16): wtmix 196608 | wtiter 131072 | ccat 4096
  uint16_t* wtmix  = (uint16_t*)d_ws;
  uint16_t* wtiter = wtmix + 196608;
  uint16_t* ccat   = wtiter + 131072;

  k0_prep<<<1296, 256, 0, stream>>>(mixw, iterw, cg, wtmix, wtiter, ccat);
  k_fused<<<2048, 1024, 0, stream>>>(f0, f1, f2, f3, wtmix, wtiter, ccat, out);
}